// Round 5
// baseline (576.779 us; speedup 1.0000x reference)
//
#include <hip/hip_runtime.h>
#include <math.h>

typedef _Float16 f16;
typedef _Float16 half8 __attribute__((ext_vector_type(8)));
typedef _Float16 h2 __attribute__((ext_vector_type(2)));
typedef float f32x4 __attribute__((ext_vector_type(4)));
typedef __attribute__((address_space(1))) const unsigned int gu32;
typedef __attribute__((address_space(3))) unsigned int lu32;

#define BB 32
#define SS 1024
#define DD 512
#define NR (BB*SS)   // 32768

// ---------- m97-style staging helpers (128B rows, 16B chunks, xor-swizzle row&7) ----------
__device__ __forceinline__ void stage128(const char* g, int ldb, char* lds,
                                         int wv, int ln) {
  #pragma unroll
  for (int r = 0; r < 4; r++) {
    int slot = r * 256 + wv * 64 + ln;
    int row = slot >> 3, cp = slot & 7;
    int c = cp ^ (row & 7);
    const char* gp = g + (size_t)row * ldb + (c << 4);
    char* lp = lds + ((slot - ln) << 4);
    __builtin_amdgcn_global_load_lds((gu32*)gp, (lu32*)lp, 16, 0, 0);
  }
}

__device__ __forceinline__ void stage64(const char* g, int ldb, char* lds,
                                        int wv, int ln) {
  #pragma unroll
  for (int r = 0; r < 2; r++) {
    int slot = r * 256 + wv * 64 + ln;
    int row = slot >> 3, cp = slot & 7;
    int c = cp ^ (row & 7);
    const char* gp = g + (size_t)row * ldb + (c << 4);
    char* lp = lds + ((slot - ln) << 4);
    __builtin_amdgcn_global_load_lds((gu32*)gp, (lu32*)lp, 16, 0, 0);
  }
}

__device__ __forceinline__ half8 frag_ld(const char* lds, int row, int kc) {
  return *(const half8*)(lds + row * 128 + ((kc ^ (row & 7)) << 4));
}

__device__ __forceinline__ f32x4 MF(half8 a, half8 b, f32x4 c) {
  return __builtin_amdgcn_mfma_f32_16x16x32_f16(a, b, c, 0, 0, 0);
}

// V slab: [512 d][32 keys] fp16, 64B rows, 4 chunks, swizzle (row^row>>2)&3
__device__ __forceinline__ void stage_v(const f16* vt_base, char* lds, int wv, int ln) {
  #pragma unroll
  for (int it = 0; it < 8; it++) {
    int slot = it * 256 + wv * 64 + ln;
    int row = slot >> 2, cp = slot & 3;
    int c = (cp ^ row ^ (row >> 2)) & 3;
    const char* gp = (const char*)(vt_base + (size_t)row * NR) + (c << 4);
    char* lp = lds + ((slot - ln) << 4);
    __builtin_amdgcn_global_load_lds((gu32*)gp, (lu32*)lp, 16, 0, 0);
  }
}

__device__ __forceinline__ half8 frag_v(const char* lds, int row, int quad) {
  return *(const half8*)(lds + row * 64 + (((quad ^ row ^ (row >> 2)) & 3) << 4));
}

// ---------------- K1: merged embedding+LN and weight-prep ----------------
__global__ __launch_bounds__(256) void k_prep(
    const int* __restrict__ inp, const float* __restrict__ wemb,
    const float* __restrict__ pemb, const float* __restrict__ gamma,
    const float* __restrict__ beta, f16* __restrict__ Xhi, f16* __restrict__ Xlo,
    const float* __restrict__ Wq, const float* __restrict__ Wk,
    const float* __restrict__ Wv, f16* __restrict__ Wqth, f16* __restrict__ Wqtl,
    f16* __restrict__ Wkth, f16* __restrict__ Wktl, f16* __restrict__ Wvt)
{
  int bid = blockIdx.x;
  int tid = threadIdx.x;
  if (bid >= NR) {               // ---- weight prep: transpose + split ----
    int d = bid - NR;
    for (int c = tid; c < DD; c += 256) {
      float q = Wq[(size_t)c * DD + d];
      float k = Wk[(size_t)c * DD + d];
      float v = Wv[(size_t)c * DD + d];
      f16 qh = (f16)q, kh = (f16)k;
      size_t o = (size_t)d * DD + c;
      Wqth[o] = qh; Wqtl[o] = (f16)(q - (float)qh);
      Wkth[o] = kh; Wktl[o] = (f16)(k - (float)kh);
      Wvt[o]  = (f16)v;
    }
    return;
  }
  // ---- embedding + layernorm -> split fp16 X ----
  int row = bid;
  int s   = row & (SS - 1);
  int tok = inp[row];
  float2 w = ((const float2*)(wemb + (size_t)tok * DD))[tid];
  float2 p = ((const float2*)(pemb + (size_t)s   * DD))[tid];
  float ex = w.x + p.x, ey = w.y + p.y;
  float sum = ex + ey, ssq = ex*ex + ey*ey;
  #pragma unroll
  for (int off = 32; off > 0; off >>= 1) {
    sum += __shfl_down(sum, off, 64);
    ssq += __shfl_down(ssq, off, 64);
  }
  __shared__ float red[10];
  int wv = tid >> 6, ln = tid & 63;
  if (ln == 0) { red[wv] = sum; red[4 + wv] = ssq; }
  __syncthreads();
  if (tid == 0) {
    float s4 = red[0] + red[1] + red[2] + red[3];
    float q4 = red[4] + red[5] + red[6] + red[7];
    float mean = s4 * (1.0f / DD);
    float var  = q4 * (1.0f / DD) - mean * mean;
    red[8] = mean; red[9] = rsqrtf(var + 1e-5f);
  }
  __syncthreads();
  float mean = red[8], rstd = red[9];
  float2 g  = ((const float2*)gamma)[tid];
  float2 bt = ((const float2*)beta)[tid];
  float ox = (ex - mean) * rstd * g.x + bt.x;
  float oy = (ey - mean) * rstd * g.y + bt.y;
  f16 hx = (f16)ox, hy = (f16)oy;
  f16 lx = (f16)(ox - (float)hx), ly = (f16)(oy - (float)hy);
  ((h2*)(Xhi + (size_t)row * DD))[tid] = (h2){hx, hy};
  ((h2*)(Xlo + (size_t)row * DD))[tid] = (h2){lx, ly};
}

// ---------------- K2: FUSED Q+K projection (split x split, 3-term, 2 B-phases) -----
__global__ __launch_bounds__(256, 2) void k_projqk(
    const f16* __restrict__ Xhi, const f16* __restrict__ Xlo,
    const f16* __restrict__ Wqth, const f16* __restrict__ Wqtl,
    const f16* __restrict__ Wkth, const f16* __restrict__ Wktl,
    f16* __restrict__ Qhi, f16* __restrict__ Qlo,
    f16* __restrict__ Khi, f16* __restrict__ Klo)
{
  __shared__ __align__(16) char Ah[16384], Al[16384], Bh[16384], Bl[16384];
  int tid = threadIdx.x, wv = tid >> 6, ln = tid & 63;
  int mw = wv & 1, nw = wv >> 1;
  int n0 = blockIdx.x * 128;   // d
  int m0 = blockIdx.y * 128;   // s
  f32x4 acc[2][4][4];
  #pragma unroll
  for (int p = 0; p < 2; p++)
    #pragma unroll
    for (int i = 0; i < 4; i++)
      #pragma unroll
      for (int j = 0; j < 4; j++) acc[p][i][j] = (f32x4)(0.0f);
  int quad = ln >> 4, l15 = ln & 15;
  for (int k0 = 0; k0 < DD; k0 += 64) {
    __syncthreads();
    stage128((const char*)(Xhi  + (size_t)m0 * DD + k0), 1024, Ah, wv, ln);
    stage128((const char*)(Xlo  + (size_t)m0 * DD + k0), 1024, Al, wv, ln);
    stage128((const char*)(Wqth + (size_t)n0 * DD + k0), 1024, Bh, wv, ln);
    stage128((const char*)(Wqtl + (size_t)n0 * DD + k0), 1024, Bl, wv, ln);
    __syncthreads();
    #pragma unroll
    for (int ks = 0; ks < 2; ks++) {
      int kc = ks * 4 + quad;
      half8 ah[4], al[4], bh[4], bl[4];
      #pragma unroll
      for (int t = 0; t < 4; t++) {
        ah[t] = frag_ld(Ah, mw * 64 + t * 16 + l15, kc);
        al[t] = frag_ld(Al, mw * 64 + t * 16 + l15, kc);
        bh[t] = frag_ld(Bh, nw * 64 + t * 16 + l15, kc);
        bl[t] = frag_ld(Bl, nw * 64 + t * 16 + l15, kc);
      }
      #pragma unroll
      for (int i = 0; i < 4; i++)
        #pragma unroll
        for (int j = 0; j < 4; j++) {
          acc[0][i][j] = MF(ah[i], bh[j], acc[0][i][j]);
          acc[0][i][j] = MF(ah[i], bl[j], acc[0][i][j]);
          acc[0][i][j] = MF(al[i], bh[j], acc[0][i][j]);
        }
    }
    __syncthreads();
    stage128((const char*)(Wkth + (size_t)n0 * DD + k0), 1024, Bh, wv, ln);
    stage128((const char*)(Wktl + (size_t)n0 * DD + k0), 1024, Bl, wv, ln);
    __syncthreads();
    #pragma unroll
    for (int ks = 0; ks < 2; ks++) {
      int kc = ks * 4 + quad;
      half8 ah[4], al[4], bh[4], bl[4];
      #pragma unroll
      for (int t = 0; t < 4; t++) {
        ah[t] = frag_ld(Ah, mw * 64 + t * 16 + l15, kc);
        al[t] = frag_ld(Al, mw * 64 + t * 16 + l15, kc);
        bh[t] = frag_ld(Bh, nw * 64 + t * 16 + l15, kc);
        bl[t] = frag_ld(Bl, nw * 64 + t * 16 + l15, kc);
      }
      #pragma unroll
      for (int i = 0; i < 4; i++)
        #pragma unroll
        for (int j = 0; j < 4; j++) {
          acc[1][i][j] = MF(ah[i], bh[j], acc[1][i][j]);
          acc[1][i][j] = MF(ah[i], bl[j], acc[1][i][j]);
          acc[1][i][j] = MF(al[i], bh[j], acc[1][i][j]);
        }
    }
  }
  #pragma unroll
  for (int i = 0; i < 4; i++)
    #pragma unroll
    for (int j = 0; j < 4; j++)
      #pragma unroll
      for (int rg = 0; rg < 4; rg++) {
        int gm = m0 + mw * 64 + i * 16 + quad * 4 + rg;
        int gn = n0 + nw * 64 + j * 16 + l15;
        size_t o = (size_t)gm * DD + gn;
        float vq = acc[0][i][j][rg];
        f16 hq = (f16)vq;
        Qhi[o] = hq; Qlo[o] = (f16)(vq - (float)hq);
        float vk = acc[1][i][j][rg];
        f16 hk = (f16)vk;
        Khi[o] = hk; Klo[o] = (f16)(vk - (float)hk);
      }
}

// ---------------- K3: Vt GEMM (plain fp16): Vt[d][s] ----------------
__global__ __launch_bounds__(256, 2) void k_vt(
    const f16* __restrict__ Wvt, const f16* __restrict__ Xhi, f16* __restrict__ Vt)
{
  __shared__ __align__(16) char Ah[16384], Bh[16384];
  int tid = threadIdx.x, wv = tid >> 6, ln = tid & 63;
  int mw = wv & 1, nw = wv >> 1;
  int n0 = blockIdx.x * 128;   // s
  int m0 = blockIdx.y * 128;   // d
  f32x4 acc[4][4];
  #pragma unroll
  for (int i = 0; i < 4; i++)
    #pragma unroll
    for (int j = 0; j < 4; j++) acc[i][j] = (f32x4)(0.0f);
  for (int k0 = 0; k0 < DD; k0 += 64) {
    __syncthreads();
    stage128((const char*)(Wvt + (size_t)m0 * DD + k0), 1024, Ah, wv, ln);
    stage128((const char*)(Xhi + (size_t)n0 * DD + k0), 1024, Bh, wv, ln);
    __syncthreads();
    int quad = ln >> 4, l15 = ln & 15;
    #pragma unroll
    for (int ks = 0; ks < 2; ks++) {
      int kc = ks * 4 + quad;
      half8 a[4], b[4];
      #pragma unroll
      for (int t = 0; t < 4; t++) {
        a[t] = frag_ld(Ah, mw * 64 + t * 16 + l15, kc);
        b[t] = frag_ld(Bh, nw * 64 + t * 16 + l15, kc);
      }
      #pragma unroll
      for (int i = 0; i < 4; i++)
        #pragma unroll
        for (int j = 0; j < 4; j++) acc[i][j] = MF(a[i], b[j], acc[i][j]);
    }
  }
  int quad = ln >> 4, l15 = ln & 15;
  #pragma unroll
  for (int i = 0; i < 4; i++)
    #pragma unroll
    for (int j = 0; j < 4; j++)
      #pragma unroll
      for (int rg = 0; rg < 4; rg++) {
        int gm = m0 + mw * 64 + i * 16 + quad * 4 + rg;   // d
        int gn = n0 + nw * 64 + j * 16 + l15;             // s
        Vt[(size_t)gm * NR + gn] = (f16)acc[i][j][rg];
      }
}

// ---------------- K4: fused flash attention (MFMA, online softmax) ----------------
// 64 q/block, 128-key tiles. QK transposed (A=K 2 tiles/wave, B=Q 4 tiles) ->
// C[key][q], per-thread softmax state = 4 q-cols (j). P -> LDS [q][key].
// PV computes O^T (A=Vt slab, B=P): wave owns d-slice [128w,128w+128).
__global__ __launch_bounds__(256, 2) void k_flash(
    const f16* __restrict__ Qhi, const f16* __restrict__ Qlo,
    const f16* __restrict__ Khi, const f16* __restrict__ Klo,
    const f16* __restrict__ Vt, float* __restrict__ O)
{
  __shared__ __align__(16) char pool[66560];
  char* Kh = pool;             // 16384: K hi, 128 rows x 64d
  char* Kl = pool + 16384;     // 16384
  char* Qh = pool + 32768;     // 8192:  Q hi, 64 rows x 64d
  char* Ql = pool + 40960;     // 8192
  char* Pl = pool + 49152;     // 64 x 272B = 17408: P [q][128 keys + pad]
  char* Vb = pool;             // V slab [512 d][32 keys] = 32768, overlays Kh/Kl
  __shared__ float wred[2][4][64];   // [max|sum][wave][q]

  int tid = threadIdx.x, wv = tid >> 6, ln = tid & 63;
  int quad = ln >> 4, l15 = ln & 15;
  int q0 = blockIdx.x * 64;
  int b  = blockIdx.y;
  const float scale = 0.044194173824159216f;   // 1/sqrt(512)

  f32x4 os[8][4];              // O^T acc: d-tile i (16d each), q-tile j
  #pragma unroll
  for (int i = 0; i < 8; i++)
    #pragma unroll
    for (int j = 0; j < 4; j++) os[i][j] = (f32x4)(0.0f);
  float m_run[4] = {-1e30f, -1e30f, -1e30f, -1e30f};
  float l_run[4] = {0.f, 0.f, 0.f, 0.f};

  const size_t qbase = (size_t)(b * SS + q0) * DD;

  for (int kt = 0; kt < SS / 128; kt++) {
    // ---- QK phase: C[key][q], 8 d-slabs ----
    f32x4 sa[2][4];
    #pragma unroll
    for (int i = 0; i < 2; i++)
      #pragma unroll
      for (int j = 0; j < 4; j++) sa[i][j] = (f32x4)(0.0f);
    const size_t kbase = (size_t)(b * SS + kt * 128) * DD;
    for (int d0 = 0; d0 < DD; d0 += 64) {
      __syncthreads();   // WAR: prior tile's V reads (Vb overlays Kh/Kl) / prior slab frag reads
      stage128((const char*)Khi + (kbase << 1) + (d0 << 1), 1024, Kh, wv, ln);
      stage128((const char*)Klo + (kbase << 1) + (d0 << 1), 1024, Kl, wv, ln);
      stage64 ((const char*)Qhi + (qbase << 1) + (d0 << 1), 1024, Qh, wv, ln);
      stage64 ((const char*)Qlo + (qbase << 1) + (d0 << 1), 1024, Ql, wv, ln);
      __syncthreads();
      #pragma unroll
      for (int ks = 0; ks < 2; ks++) {
        int kc = ks * 4 + quad;
        half8 ah[2], al2[2], bh[4], bl[4];
        #pragma unroll
        for (int i = 0; i < 2; i++) {
          ah[i]  = frag_ld(Kh, 32 * wv + i * 16 + l15, kc);
          al2[i] = frag_ld(Kl, 32 * wv + i * 16 + l15, kc);
        }
        #pragma unroll
        for (int j = 0; j < 4; j++) {
          bh[j] = frag_ld(Qh, j * 16 + l15, kc);
          bl[j] = frag_ld(Ql, j * 16 + l15, kc);
        }
        #pragma unroll
        for (int i = 0; i < 2; i++)
          #pragma unroll
          for (int j = 0; j < 4; j++) {
            sa[i][j] = MF(ah[i], bh[j], sa[i][j]);
            sa[i][j] = MF(ah[i], bl[j], sa[i][j]);
            sa[i][j] = MF(al2[i], bh[j], sa[i][j]);
          }
      }
    }
    // ---- online softmax (transposed layout: thread's q-cols = 16j + l15) ----
    #pragma unroll
    for (int i = 0; i < 2; i++)
      #pragma unroll
      for (int j = 0; j < 4; j++) sa[i][j] *= scale;
    float al4[4];
    #pragma unroll
    for (int j = 0; j < 4; j++) {
      float mx = sa[0][j][0];
      #pragma unroll
      for (int rg = 1; rg < 4; rg++) mx = fmaxf(mx, sa[0][j][rg]);
      #pragma unroll
      for (int rg = 0; rg < 4; rg++) mx = fmaxf(mx, sa[1][j][rg]);
      mx = fmaxf(mx, __shfl_xor(mx, 16, 64));
      mx = fmaxf(mx, __shfl_xor(mx, 32, 64));
      if (quad == 0) wred[0][wv][16 * j + l15] = mx;
    }
    __syncthreads();
    #pragma unroll
    for (int j = 0; j < 4; j++) {
      float mt = fmaxf(fmaxf(wred[0][0][16 * j + l15], wred[0][1][16 * j + l15]),
                       fmaxf(wred[0][2][16 * j + l15], wred[0][3][16 * j + l15]));
      float mnew = fmaxf(m_run[j], mt);
      al4[j] = __expf(m_run[j] - mnew);
      m_run[j] = mnew;
    }
    #pragma unroll
    for (int j = 0; j < 4; j++) {
      float ps = 0.f;
      #pragma unroll
      for (int i = 0; i < 2; i++)
        #pragma unroll
        for (int rg = 0; rg < 4; rg++) {
          float p = __expf(sa[i][j][rg] - m_run[j]);
          ps += p;
          int key = 32 * wv + 16 * i + quad * 4 + rg;
          *(f16*)(Pl + (16 * j + l15) * 272 + key * 2) = (f16)p;
        }
      ps += __shfl_xor(ps, 16, 64);
      ps += __shfl_xor(ps, 32, 64);
      if (quad == 0) wred[1][wv][16 * j + l15] = ps;
    }
    __syncthreads();   // publishes P + wavesum
    #pragma unroll
    for (int j = 0; j < 4; j++) {
      float ts = wred[1][0][16 * j + l15] + wred[1][1][16 * j + l15] +
                 wred[1][2][16 * j + l15] + wred[1][3][16 * j + l15];
      l_run[j] = l_run[j] * al4[j] + ts;
    }
    // rescale O^T
    #pragma unroll
    for (int i = 0; i < 8; i++)
      #pragma unroll
      for (int j = 0; j < 4; j++) os[i][j] *= al4[j];
    // ---- PV phase: 4 slabs of 32 keys; V slab [512 d][32 k] into Vb ----
    for (int sl = 0; sl < 4; sl++) {
      __syncthreads();   // WAR on Vb (K staging or prior slab reads)
      stage_v(Vt + (size_t)b * SS + kt * 128 + sl * 32, Vb, wv, ln);
      __syncthreads();
      half8 pf[4];
      #pragma unroll
      for (int j = 0; j < 4; j++)
        pf[j] = *(const half8*)(Pl + (16 * j + l15) * 272 + sl * 64 + quad * 16);
      #pragma unroll
      for (int i = 0; i < 8; i++) {
        half8 va = frag_v(Vb, 128 * wv + 16 * i + l15, quad);
        #pragma unroll
        for (int j = 0; j < 4; j++) os[i][j] = MF(va, pf[j], os[i][j]);
      }
    }
  }
  // ---- epilogue: normalize, store O (O^T regs -> [q][d] via rg=consecutive d) ----
  float inv[4];
  #pragma unroll
  for (int j = 0; j < 4; j++) inv[j] = 1.0f / l_run[j];
  #pragma unroll
  for (int i = 0; i < 8; i++)
    #pragma unroll
    for (int j = 0; j < 4; j++) {
      f32x4 w = os[i][j] * inv[j];
      int gq = q0 + 16 * j + l15;
      int gd = 128 * wv + 16 * i + 4 * quad;
      *(f32x4*)&O[((size_t)b * SS + gq) * DD + gd] = w;
    }
}

extern "C" void kernel_launch(void* const* d_in, const int* in_sizes, int n_in,
                              void* d_out, int out_size, void* d_ws, size_t ws_size,
                              hipStream_t stream) {
  const int*   inp   = (const int*)d_in[0];
  const float* wemb  = (const float*)d_in[1];
  const float* pemb  = (const float*)d_in[2];
  const float* gamma = (const float*)d_in[3];
  const float* beta  = (const float*)d_in[4];
  const float* Wk    = (const float*)d_in[5];
  const float* Wq    = (const float*)d_in[6];
  const float* Wv    = (const float*)d_in[7];

  // ws (192 MiB): [Xhi 32M][Xlo 32M][Qhi 32M][Qlo 32M][Khi 32M][Klo 32M]
  // Vt (32M) overlays Xlo after k_projqk (Xlo dead once projqk is done).
  char* ws = (char*)d_ws;
  f16* Xhi = (f16*)ws;
  f16* Xlo = (f16*)(ws + ((size_t)32 << 20));
  f16* Qhi = (f16*)(ws + ((size_t)64 << 20));
  f16* Qlo = (f16*)(ws + ((size_t)96 << 20));
  f16* Khi = (f16*)(ws + ((size_t)128 << 20));
  f16* Klo = (f16*)(ws + ((size_t)160 << 20));
  f16* Vt  = (f16*)(ws + ((size_t)32 << 20));     // over Xlo

  f16* Wqth = (f16*)d_out;                        // weights parked in d_out head,
  f16* Wqtl = Wqth + (size_t)DD * DD;             // consumed before k_flash writes O
  f16* Wkth = Wqtl + (size_t)DD * DD;
  f16* Wktl = Wkth + (size_t)DD * DD;
  f16* Wvt  = Wktl + (size_t)DD * DD;

  k_prep<<<NR + DD, 256, 0, stream>>>(inp, wemb, pemb, gamma, beta, Xhi, Xlo,
                                      Wq, Wk, Wv, Wqth, Wqtl, Wkth, Wktl, Wvt);
  k_projqk<<<dim3(DD / 128, NR / 128), 256, 0, stream>>>(
      Xhi, Xlo, Wqth, Wqtl, Wkth, Wktl, Qhi, Qlo, Khi, Klo);
  k_vt<<<dim3(NR / 128, DD / 128), 256, 0, stream>>>(Wvt, Xhi, Vt);
  k_flash<<<dim3(SS / 64, BB), 256, 0, stream>>>(Qhi, Qlo, Khi, Klo, Vt, (float*)d_out);
}

// Round 6
// 508.772 us; speedup vs baseline: 1.1337x; 1.1337x over previous
//
#include <hip/hip_runtime.h>
#include <math.h>

typedef _Float16 f16;
typedef _Float16 half8 __attribute__((ext_vector_type(8)));
typedef _Float16 hv2 __attribute__((ext_vector_type(2)));
typedef _Float16 hv4 __attribute__((ext_vector_type(4)));
typedef float f32x4 __attribute__((ext_vector_type(4)));
typedef __attribute__((address_space(1))) const unsigned int gu32;
typedef __attribute__((address_space(3))) unsigned int lu32;

#define BB 32
#define SS 1024
#define DD 512
#define NR (BB*SS)   // 32768
#define CH 16        // batches per S chunk (S chunk = 16*1024*1024 fp32 = 64 MiB = d_out)

// ---------- m97-style staging helpers (128B rows, 16B chunks, xor-swizzle row&7) ----------
__device__ __forceinline__ void stage128(const char* g, int ldb, char* lds,
                                         int wv, int ln) {
  #pragma unroll
  for (int r = 0; r < 4; r++) {
    int slot = r * 256 + wv * 64 + ln;
    int row = slot >> 3, cp = slot & 7;
    int c = cp ^ (row & 7);
    const char* gp = g + (size_t)row * ldb + (c << 4);
    char* lp = lds + ((slot - ln) << 4);
    __builtin_amdgcn_global_load_lds((gu32*)gp, (lu32*)lp, 16, 0, 0);
  }
}

__device__ __forceinline__ void stage64(const char* g, int ldb, char* lds,
                                        int wv, int ln) {
  #pragma unroll
  for (int r = 0; r < 2; r++) {
    int slot = r * 256 + wv * 64 + ln;
    int row = slot >> 3, cp = slot & 7;
    int c = cp ^ (row & 7);
    const char* gp = g + (size_t)row * ldb + (c << 4);
    char* lp = lds + ((slot - ln) << 4);
    __builtin_amdgcn_global_load_lds((gu32*)gp, (lu32*)lp, 16, 0, 0);
  }
}

__device__ __forceinline__ half8 frag_ld(const char* lds, int row, int kc) {
  return *(const half8*)(lds + row * 128 + ((kc ^ (row & 7)) << 4));
}

__device__ __forceinline__ f32x4 MF(half8 a, half8 b, f32x4 c) {
  return __builtin_amdgcn_mfma_f32_16x16x32_f16(a, b, c, 0, 0, 0);
}

// ---------------- K1: merged embedding+LN and LDS-tiled weight transpose/split -----
__global__ __launch_bounds__(256) void k_prep(
    const int* __restrict__ inp, const float* __restrict__ wemb,
    const float* __restrict__ pemb, const float* __restrict__ gamma,
    const float* __restrict__ beta, f16* __restrict__ Xhi, f16* __restrict__ Xlo,
    const float* __restrict__ Wq, const float* __restrict__ Wk,
    const float* __restrict__ Wv, f16* __restrict__ Wqth, f16* __restrict__ Wqtl,
    f16* __restrict__ Wkth, f16* __restrict__ Wktl, f16* __restrict__ Wvt)
{
  int bid = blockIdx.x;
  int tid = threadIdx.x;
  __shared__ float red[10];
  __shared__ float Lt[64][65];
  if (bid >= NR) {               // ---- weight transpose + split, 64x64 LDS tiles ----
    int t  = bid - NR;           // 0..191
    int mz = t >> 6;             // 0=Wq 1=Wk 2=Wv
    int tt = t & 63;
    int tr = tt >> 3, tc = tt & 7;    // input: rows c in tr*64.., cols d in tc*64..
    const float* W = (mz == 0) ? Wq : (mz == 1) ? Wk : Wv;
    int rr = tid >> 4;           // 0..15
    int c4 = (tid & 15) * 4;
    #pragma unroll
    for (int p = 0; p < 4; p++) {
      float4 v = *(const float4*)&W[(size_t)(tr * 64 + p * 16 + rr) * DD + tc * 64 + c4];
      Lt[p * 16 + rr][c4 + 0] = v.x; Lt[p * 16 + rr][c4 + 1] = v.y;
      Lt[p * 16 + rr][c4 + 2] = v.z; Lt[p * 16 + rr][c4 + 3] = v.w;
    }
    __syncthreads();
    #pragma unroll
    for (int p = 0; p < 4; p++) {
      int dl = p * 16 + rr;
      float v0 = Lt[c4 + 0][dl], v1 = Lt[c4 + 1][dl];
      float v2 = Lt[c4 + 2][dl], v3 = Lt[c4 + 3][dl];
      size_t o = (size_t)(tc * 64 + dl) * DD + tr * 64 + c4;
      f16 h0 = (f16)v0, h1 = (f16)v1, h2 = (f16)v2, h3 = (f16)v3;
      if (mz == 2) {
        *(hv4*)&Wvt[o] = (hv4){h0, h1, h2, h3};
      } else {
        hv4 hi = {h0, h1, h2, h3};
        hv4 lo = {(f16)(v0 - (float)h0), (f16)(v1 - (float)h1),
                  (f16)(v2 - (float)h2), (f16)(v3 - (float)h3)};
        if (mz == 0) { *(hv4*)&Wqth[o] = hi; *(hv4*)&Wqtl[o] = lo; }
        else         { *(hv4*)&Wkth[o] = hi; *(hv4*)&Wktl[o] = lo; }
      }
    }
    return;
  }
  // ---- embedding + layernorm -> split fp16 X ----
  int row = bid;
  int s   = row & (SS - 1);
  int tok = inp[row];
  float2 w = ((const float2*)(wemb + (size_t)tok * DD))[tid];
  float2 p = ((const float2*)(pemb + (size_t)s   * DD))[tid];
  float ex = w.x + p.x, ey = w.y + p.y;
  float sum = ex + ey, ssq = ex*ex + ey*ey;
  #pragma unroll
  for (int off = 32; off > 0; off >>= 1) {
    sum += __shfl_down(sum, off, 64);
    ssq += __shfl_down(ssq, off, 64);
  }
  int wv = tid >> 6, ln = tid & 63;
  if (ln == 0) { red[wv] = sum; red[4 + wv] = ssq; }
  __syncthreads();
  if (tid == 0) {
    float s4 = red[0] + red[1] + red[2] + red[3];
    float q4 = red[4] + red[5] + red[6] + red[7];
    float mean = s4 * (1.0f / DD);
    float var  = q4 * (1.0f / DD) - mean * mean;
    red[8] = mean; red[9] = rsqrtf(var + 1e-5f);
  }
  __syncthreads();
  float mean = red[8], rstd = red[9];
  float2 g  = ((const float2*)gamma)[tid];
  float2 bt = ((const float2*)beta)[tid];
  float ox = (ex - mean) * rstd * g.x + bt.x;
  float oy = (ey - mean) * rstd * g.y + bt.y;
  f16 hx = (f16)ox, hy = (f16)oy;
  f16 lx = (f16)(ox - (float)hx), ly = (f16)(oy - (float)hy);
  ((hv2*)(Xhi + (size_t)row * DD))[tid] = (hv2){hx, hy};
  ((hv2*)(Xlo + (size_t)row * DD))[tid] = (hv2){lx, ly};
}

// ---------------- K2: FUSED Q+K projection (split x split, 3-term, 2 B-phases) -----
__global__ __launch_bounds__(256, 2) void k_projqk(
    const f16* __restrict__ Xhi, const f16* __restrict__ Xlo,
    const f16* __restrict__ Wqth, const f16* __restrict__ Wqtl,
    const f16* __restrict__ Wkth, const f16* __restrict__ Wktl,
    f16* __restrict__ Qhi, f16* __restrict__ Qlo,
    f16* __restrict__ Khi, f16* __restrict__ Klo)
{
  __shared__ __align__(16) char Ah[16384], Al[16384], Bh[16384], Bl[16384];
  int tid = threadIdx.x, wv = tid >> 6, ln = tid & 63;
  int mw = wv & 1, nw = wv >> 1;
  int n0 = blockIdx.x * 128;   // d
  int m0 = blockIdx.y * 128;   // s
  f32x4 acc[2][4][4];
  #pragma unroll
  for (int p = 0; p < 2; p++)
    #pragma unroll
    for (int i = 0; i < 4; i++)
      #pragma unroll
      for (int j = 0; j < 4; j++) acc[p][i][j] = (f32x4)(0.0f);
  int quad = ln >> 4, l15 = ln & 15;
  for (int k0 = 0; k0 < DD; k0 += 64) {
    __syncthreads();
    stage128((const char*)(Xhi  + (size_t)m0 * DD + k0), 1024, Ah, wv, ln);
    stage128((const char*)(Xlo  + (size_t)m0 * DD + k0), 1024, Al, wv, ln);
    stage128((const char*)(Wqth + (size_t)n0 * DD + k0), 1024, Bh, wv, ln);
    stage128((const char*)(Wqtl + (size_t)n0 * DD + k0), 1024, Bl, wv, ln);
    __syncthreads();
    #pragma unroll
    for (int ks = 0; ks < 2; ks++) {
      int kc = ks * 4 + quad;
      half8 ah[4], al[4], bh[4], bl[4];
      #pragma unroll
      for (int t = 0; t < 4; t++) {
        ah[t] = frag_ld(Ah, mw * 64 + t * 16 + l15, kc);
        al[t] = frag_ld(Al, mw * 64 + t * 16 + l15, kc);
        bh[t] = frag_ld(Bh, nw * 64 + t * 16 + l15, kc);
        bl[t] = frag_ld(Bl, nw * 64 + t * 16 + l15, kc);
      }
      #pragma unroll
      for (int i = 0; i < 4; i++)
        #pragma unroll
        for (int j = 0; j < 4; j++) {
          acc[0][i][j] = MF(ah[i], bh[j], acc[0][i][j]);
          acc[0][i][j] = MF(ah[i], bl[j], acc[0][i][j]);
          acc[0][i][j] = MF(al[i], bh[j], acc[0][i][j]);
        }
    }
    __syncthreads();
    stage128((const char*)(Wkth + (size_t)n0 * DD + k0), 1024, Bh, wv, ln);
    stage128((const char*)(Wktl + (size_t)n0 * DD + k0), 1024, Bl, wv, ln);
    __syncthreads();
    #pragma unroll
    for (int ks = 0; ks < 2; ks++) {
      int kc = ks * 4 + quad;
      half8 ah[4], al[4], bh[4], bl[4];
      #pragma unroll
      for (int t = 0; t < 4; t++) {
        ah[t] = frag_ld(Ah, mw * 64 + t * 16 + l15, kc);
        al[t] = frag_ld(Al, mw * 64 + t * 16 + l15, kc);
        bh[t] = frag_ld(Bh, nw * 64 + t * 16 + l15, kc);
        bl[t] = frag_ld(Bl, nw * 64 + t * 16 + l15, kc);
      }
      #pragma unroll
      for (int i = 0; i < 4; i++)
        #pragma unroll
        for (int j = 0; j < 4; j++) {
          acc[1][i][j] = MF(ah[i], bh[j], acc[1][i][j]);
          acc[1][i][j] = MF(ah[i], bl[j], acc[1][i][j]);
          acc[1][i][j] = MF(al[i], bh[j], acc[1][i][j]);
        }
    }
  }
  #pragma unroll
  for (int i = 0; i < 4; i++)
    #pragma unroll
    for (int j = 0; j < 4; j++)
      #pragma unroll
      for (int rg = 0; rg < 4; rg++) {
        int gm = m0 + mw * 64 + i * 16 + quad * 4 + rg;
        int gn = n0 + nw * 64 + j * 16 + l15;
        size_t o = (size_t)gm * DD + gn;
        float vq = acc[0][i][j][rg];
        f16 hq = (f16)vq;
        Qhi[o] = hq; Qlo[o] = (f16)(vq - (float)hq);
        float vk = acc[1][i][j][rg];
        f16 hk = (f16)vk;
        Khi[o] = hk; Klo[o] = (f16)(vk - (float)hk);
      }
}

// ---------------- K3: Vt GEMM (plain fp16): Vt[d][s] ----------------
__global__ __launch_bounds__(256, 2) void k_vt(
    const f16* __restrict__ Wvt, const f16* __restrict__ Xhi, f16* __restrict__ Vt)
{
  __shared__ __align__(16) char Ah[16384], Bh[16384];
  int tid = threadIdx.x, wv = tid >> 6, ln = tid & 63;
  int mw = wv & 1, nw = wv >> 1;
  int n0 = blockIdx.x * 128;   // s
  int m0 = blockIdx.y * 128;   // d
  f32x4 acc[4][4];
  #pragma unroll
  for (int i = 0; i < 4; i++)
    #pragma unroll
    for (int j = 0; j < 4; j++) acc[i][j] = (f32x4)(0.0f);
  for (int k0 = 0; k0 < DD; k0 += 64) {
    __syncthreads();
    stage128((const char*)(Wvt + (size_t)m0 * DD + k0), 1024, Ah, wv, ln);
    stage128((const char*)(Xhi + (size_t)n0 * DD + k0), 1024, Bh, wv, ln);
    __syncthreads();
    int quad = ln >> 4, l15 = ln & 15;
    #pragma unroll
    for (int ks = 0; ks < 2; ks++) {
      int kc = ks * 4 + quad;
      half8 a[4], b[4];
      #pragma unroll
      for (int t = 0; t < 4; t++) {
        a[t] = frag_ld(Ah, mw * 64 + t * 16 + l15, kc);
        b[t] = frag_ld(Bh, nw * 64 + t * 16 + l15, kc);
      }
      #pragma unroll
      for (int i = 0; i < 4; i++)
        #pragma unroll
        for (int j = 0; j < 4; j++) acc[i][j] = MF(a[i], b[j], acc[i][j]);
    }
  }
  int quad = ln >> 4, l15 = ln & 15;
  #pragma unroll
  for (int i = 0; i < 4; i++)
    #pragma unroll
    for (int j = 0; j < 4; j++)
      #pragma unroll
      for (int rg = 0; rg < 4; rg++) {
        int gm = m0 + mw * 64 + i * 16 + quad * 4 + rg;   // d
        int gn = n0 + nw * 64 + j * 16 + l15;             // s
        Vt[(size_t)gm * NR + gn] = (f16)acc[i][j][rg];
      }
}

// ---------------- K4: S = Q K^T / sqrt(D) — 64q x 256k blocks, 16-batch chunk -------
__global__ __launch_bounds__(256, 2) void k_qk(
    const f16* __restrict__ Qhi, const f16* __restrict__ Qlo,
    const f16* __restrict__ Khi, const f16* __restrict__ Klo,
    float* __restrict__ S, int chunk)
{
  __shared__ __align__(16) char Ah[8192], Al[8192], Bh[16384], Bl[16384];
  int tid = threadIdx.x, wv = tid >> 6, ln = tid & 63;
  int n0 = blockIdx.x * 256;          // key base
  int m0 = blockIdx.y * 64;           // query base
  int z  = blockIdx.z;                // batch within chunk (0..15)
  size_t brow = ((size_t)chunk * CH + z) * SS;
  f32x4 acc[2][4][2];
  #pragma unroll
  for (int p = 0; p < 2; p++)
    #pragma unroll
    for (int i = 0; i < 4; i++)
      #pragma unroll
      for (int j = 0; j < 2; j++) acc[p][i][j] = (f32x4)(0.0f);
  int quad = ln >> 4, l15 = ln & 15;
  for (int k0 = 0; k0 < DD; k0 += 64) {
    __syncthreads();
    stage64 ((const char*)(Qhi + (brow + m0) * DD + k0), 1024, Ah, wv, ln);
    stage64 ((const char*)(Qlo + (brow + m0) * DD + k0), 1024, Al, wv, ln);
    stage128((const char*)(Khi + (brow + n0) * DD + k0), 1024, Bh, wv, ln);
    stage128((const char*)(Klo + (brow + n0) * DD + k0), 1024, Bl, wv, ln);
    __syncthreads();
    #pragma unroll
    for (int ks = 0; ks < 2; ks++) {
      int kc = ks * 4 + quad;
      half8 ah[4], al[4], bh[2], bl[2];
      #pragma unroll
      for (int t = 0; t < 4; t++) {
        ah[t] = frag_ld(Ah, t * 16 + l15, kc);
        al[t] = frag_ld(Al, t * 16 + l15, kc);
      }
      #pragma unroll
      for (int t = 0; t < 2; t++) {
        bh[t] = frag_ld(Bh, wv * 32 + t * 16 + l15, kc);
        bl[t] = frag_ld(Bl, wv * 32 + t * 16 + l15, kc);
      }
      #pragma unroll
      for (int i = 0; i < 4; i++)
        #pragma unroll
        for (int j = 0; j < 2; j++) {
          acc[0][i][j] = MF(ah[i], bh[j], acc[0][i][j]);
          acc[0][i][j] = MF(ah[i], bl[j], acc[0][i][j]);
          acc[0][i][j] = MF(al[i], bh[j], acc[0][i][j]);
        }
    }
    __syncthreads();
    stage128((const char*)(Khi + (brow + n0 + 128) * DD + k0), 1024, Bh, wv, ln);
    stage128((const char*)(Klo + (brow + n0 + 128) * DD + k0), 1024, Bl, wv, ln);
    __syncthreads();
    #pragma unroll
    for (int ks = 0; ks < 2; ks++) {
      int kc = ks * 4 + quad;
      half8 ah[4], al[4], bh[2], bl[2];
      #pragma unroll
      for (int t = 0; t < 4; t++) {
        ah[t] = frag_ld(Ah, t * 16 + l15, kc);
        al[t] = frag_ld(Al, t * 16 + l15, kc);
      }
      #pragma unroll
      for (int t = 0; t < 2; t++) {
        bh[t] = frag_ld(Bh, wv * 32 + t * 16 + l15, kc);
        bl[t] = frag_ld(Bl, wv * 32 + t * 16 + l15, kc);
      }
      #pragma unroll
      for (int i = 0; i < 4; i++)
        #pragma unroll
        for (int j = 0; j < 2; j++) {
          acc[1][i][j] = MF(ah[i], bh[j], acc[1][i][j]);
          acc[1][i][j] = MF(ah[i], bl[j], acc[1][i][j]);
          acc[1][i][j] = MF(al[i], bh[j], acc[1][i][j]);
        }
    }
  }
  const float scale = 0.044194173824159216f;   // 1/sqrt(512)
  #pragma unroll
  for (int p = 0; p < 2; p++)
    #pragma unroll
    for (int i = 0; i < 4; i++)
      #pragma unroll
      for (int j = 0; j < 2; j++)
        #pragma unroll
        for (int rg = 0; rg < 4; rg++) {
          int gm = m0 + i * 16 + quad * 4 + rg;
          int gn = n0 + p * 128 + wv * 32 + j * 16 + l15;
          S[((size_t)z * SS + gm) * SS + gn] = acc[p][i][j][rg] * scale;
        }
}

// ---------------- K5: row softmax S(fp32, d_out) -> P(fp16) ----------------
__global__ __launch_bounds__(256) void k_sm(
    const float* __restrict__ S, f16* __restrict__ P)
{
  int rc = blockIdx.x;                 // row within chunk, 0..16383
  int tid = threadIdx.x;
  const float* row = S + (size_t)rc * SS;
  float4 v = ((const float4*)row)[tid];
  float mx = fmaxf(fmaxf(v.x, v.y), fmaxf(v.z, v.w));
  #pragma unroll
  for (int off = 32; off > 0; off >>= 1) mx = fmaxf(mx, __shfl_xor(mx, off, 64));
  __shared__ float red[10];
  int wv = tid >> 6;
  if ((tid & 63) == 0) red[wv] = mx;
  __syncthreads();
  if (tid == 0) red[8] = fmaxf(fmaxf(red[0], red[1]), fmaxf(red[2], red[3]));
  __syncthreads();
  mx = red[8];
  float e0 = __expf(v.x - mx), e1 = __expf(v.y - mx);
  float e2 = __expf(v.z - mx), e3 = __expf(v.w - mx);
  float sm = e0 + e1 + e2 + e3;
  #pragma unroll
  for (int off = 32; off > 0; off >>= 1) sm += __shfl_xor(sm, off, 64);
  if ((tid & 63) == 0) red[4 + wv] = sm;
  __syncthreads();
  if (tid == 0) red[9] = red[4] + red[5] + red[6] + red[7];
  __syncthreads();
  float inv = 1.0f / red[9];
  ((hv4*)(P + (size_t)rc * SS))[tid] =
      (hv4){(f16)(e0 * inv), (f16)(e1 * inv), (f16)(e2 * inv), (f16)(e3 * inv)};
}

// ---------------- K6: O = P V  (plain fp16 MFMA) ----------------
__global__ __launch_bounds__(256, 2) void k_pv(
    const f16* __restrict__ P0, const f16* __restrict__ P1,
    const f16* __restrict__ Vt, float* __restrict__ O)
{
  __shared__ __align__(16) char Ah[16384], Bh[16384];
  int tid = threadIdx.x, wv = tid >> 6, ln = tid & 63;
  int mw = wv & 1, nw = wv >> 1;
  int n0 = blockIdx.x * 128;          // d_out
  int m0 = blockIdx.y * 128;          // query (within batch)
  int b  = blockIdx.z;
  const f16* Pbase = (b < CH) ? P0 : P1;
  const char* Pt = (const char*)(Pbase + ((size_t)((b & (CH - 1)) * SS + m0)) * SS);
  f32x4 acc[4][4];
  #pragma unroll
  for (int i = 0; i < 4; i++)
    #pragma unroll
    for (int j = 0; j < 4; j++) acc[i][j] = (f32x4)(0.0f);
  for (int k0 = 0; k0 < SS; k0 += 64) {
    __syncthreads();
    stage128(Pt + k0 * 2, 2048, Ah, wv, ln);
    stage128((const char*)(Vt + (size_t)n0 * NR + (size_t)b * SS + k0), NR * 2, Bh, wv, ln);
    __syncthreads();
    int quad = ln >> 4, l15 = ln & 15;
    #pragma unroll
    for (int ks = 0; ks < 2; ks++) {
      int kc = ks * 4 + quad;
      half8 a[4], bf[4];
      #pragma unroll
      for (int t = 0; t < 4; t++) {
        a[t]  = frag_ld(Ah, mw * 64 + t * 16 + l15, kc);
        bf[t] = frag_ld(Bh, nw * 64 + t * 16 + l15, kc);
      }
      #pragma unroll
      for (int i = 0; i < 4; i++)
        #pragma unroll
        for (int j = 0; j < 4; j++) acc[i][j] = MF(a[i], bf[j], acc[i][j]);
    }
  }
  int quad = ln >> 4, l15 = ln & 15;
  #pragma unroll
  for (int i = 0; i < 4; i++)
    #pragma unroll
    for (int j = 0; j < 4; j++)
      #pragma unroll
      for (int rg = 0; rg < 4; rg++) {
        int gm = m0 + mw * 64 + i * 16 + quad * 4 + rg;
        int gn = n0 + nw * 64 + j * 16 + l15;
        O[((size_t)b * SS + gm) * DD + gn] = acc[i][j][rg];
      }
}

extern "C" void kernel_launch(void* const* d_in, const int* in_sizes, int n_in,
                              void* d_out, int out_size, void* d_ws, size_t ws_size,
                              hipStream_t stream) {
  const int*   inp   = (const int*)d_in[0];
  const float* wemb  = (const float*)d_in[1];
  const float* pemb  = (const float*)d_in[2];
  const float* gamma = (const float*)d_in[3];
  const float* beta  = (const float*)d_in[4];
  const float* Wk    = (const float*)d_in[5];
  const float* Wq    = (const float*)d_in[6];
  const float* Wv    = (const float*)d_in[7];

  // ws (192 MiB): [Xhi 32M][Xlo 32M][Qhi 32M][Qlo 32M][Khi 32M][Klo 32M]
  // overlays: Vt -> Xlo (Xlo dead after projqk); P0 -> Xhi (dead after vt);
  //           P1 -> Qhi (dead after qk chunk1). S chunks (64 MiB fp32) -> d_out.
  char* ws = (char*)d_ws;
  f16* Xhi = (f16*)ws;
  f16* Xlo = (f16*)(ws + ((size_t)32 << 20));
  f16* Qhi = (f16*)(ws + ((size_t)64 << 20));
  f16* Qlo = (f16*)(ws + ((size_t)96 << 20));
  f16* Khi = (f16*)(ws + ((size_t)128 << 20));
  f16* Klo = (f16*)(ws + ((size_t)160 << 20));
  f16* Vt  = (f16*)(ws + ((size_t)32 << 20));     // over Xlo
  f16* P0  = (f16*)ws;                            // over Xhi
  f16* P1  = (f16*)(ws + ((size_t)64 << 20));     // over Qhi

  f16* Wqth = (f16*)d_out;                        // weights parked in d_out head;
  f16* Wqtl = Wqth + (size_t)DD * DD;             // consumed before qk writes S there
  f16* Wkth = Wqtl + (size_t)DD * DD;
  f16* Wktl = Wkth + (size_t)DD * DD;
  f16* Wvt  = Wktl + (size_t)DD * DD;

  float* Sb = (float*)d_out;

  k_prep<<<NR + 192, 256, 0, stream>>>(inp, wemb, pemb, gamma, beta, Xhi, Xlo,
                                       Wq, Wk, Wv, Wqth, Wqtl, Wkth, Wktl, Wvt);
  k_projqk<<<dim3(DD / 128, NR / 128), 256, 0, stream>>>(
      Xhi, Xlo, Wqth, Wqtl, Wkth, Wktl, Qhi, Qlo, Khi, Klo);
  k_vt<<<dim3(NR / 128, DD / 128), 256, 0, stream>>>(Wvt, Xhi, Vt);
  for (int c = 0; c < 2; c++) {
    k_qk<<<dim3(SS / 256, SS / 64, CH), 256, 0, stream>>>(Qhi, Qlo, Khi, Klo, Sb, c);
    k_sm<<<CH * SS, 256, 0, stream>>>(Sb, c == 0 ? P0 : P1);
  }
  k_pv<<<dim3(DD / 128, SS / 128, BB), 256, 0, stream>>>(P0, P1, Vt, (float*)d_out);
}